// Round 1
// baseline (2598.376 us; speedup 1.0000x reference)
//
#include <hip/hip_runtime.h>

// RNN scan: h_{t+1} = 0.8*h_t + 0.2*(relu(h_t @ W_rec^T + b_rec + inp_t) + rn_t)
// B=128 independent chains -> 128 blocks, one chain per block.
// Thread n owns W_rec row n in fp16 registers (256 VGPRs); h broadcast via LDS.

#define B_  128
#define T_  512
#define N_  512
#define IN_ 6

typedef _Float16 half2_t __attribute__((ext_vector_type(2)));
typedef _Float16 half8_t __attribute__((ext_vector_type(8)));

#if __has_builtin(__builtin_amdgcn_fdot2)
#define HAVE_FDOT2 1
#else
#define HAVE_FDOT2 0
#endif

__device__ __forceinline__ float dot2_acc(half2_t a, half2_t b, float c) {
#if HAVE_FDOT2
    return __builtin_amdgcn_fdot2(a, b, c, false);
#else
    c = fmaf((float)a[0], (float)b[0], c);
    c = fmaf((float)a[1], (float)b[1], c);
    return c;
#endif
}

__global__ __launch_bounds__(512) void rnn_scan_kernel(
    const float* __restrict__ u,     // [B,T,IN]
    const float* __restrict__ unz,   // [B,T,IN] input noise
    const float* __restrict__ rnz,   // [B,T,N]  recurrent noise
    const float* __restrict__ Wrec,  // [N,N]
    const float* __restrict__ brec,  // [N]
    const float* __restrict__ Win,   // [N,IN]
    float* __restrict__ out)         // [B,T,N]
{
    const int b = blockIdx.x;
    const int n = threadIdx.x;

    __shared__ __align__(16) _Float16 hbuf[2][N_];

    // ---- one-time: W_rec row n -> fp16 register pairs (256 VGPRs) ----
    half2_t w[N_ / 2];
    {
        const float2* wrow = (const float2*)(Wrec + (size_t)n * N_);
#pragma unroll
        for (int j = 0; j < N_ / 2; ++j) {
            float2 f = wrow[j];
            w[j] = half2_t{(_Float16)f.x, (_Float16)f.y};
        }
    }
    float win[IN_];
#pragma unroll
    for (int i = 0; i < IN_; ++i) win[i] = Win[n * IN_ + i];
    const float br = brec[n];

    const float alpha  = 0.2f;
    const float one_m  = 0.8f;
    const float nscale = 0.6324555320336759f; // sqrt(2/alpha * sigma^2) = sqrt(0.4)

    // state t=0 is zeros
    float h = 0.0f;
    float* ob = out + (size_t)b * T_ * N_;
    ob[n] = 0.0f;
    hbuf[0][n] = (_Float16)0.0f;
    __syncthreads();

    const float* ub = u   + (size_t)b * T_ * IN_;
    const float* nb = unz + (size_t)b * T_ * IN_;
    const float* rb = rnz + (size_t)b * T_ * N_;

    for (int t = 0; t < T_ - 1; ++t) {
        // hoisted loads: latency hides under the dot-product loop
        const float rn = rb[t * N_ + n];

        // inp_t[n] = sum_i Win[n,i] * (u[b,t,i] + nscale*unz[b,t,i])  (wave-uniform u reads)
        float inp = br;
#pragma unroll
        for (int i = 0; i < IN_; ++i)
            inp = fmaf(win[i], fmaf(nscale, nb[t * IN_ + i], ub[t * IN_ + i]), inp);

        const _Float16* hb = hbuf[t & 1];
        float a0 = inp, a1 = 0.0f, a2 = 0.0f, a3 = 0.0f;
#pragma unroll
        for (int j = 0; j < N_ / 8; ++j) {
            half8_t hv = *(const half8_t*)(hb + j * 8); // broadcast b128, conflict-free
            a0 = dot2_acc(w[j * 4 + 0], half2_t{hv[0], hv[1]}, a0);
            a1 = dot2_acc(w[j * 4 + 1], half2_t{hv[2], hv[3]}, a1);
            a2 = dot2_acc(w[j * 4 + 2], half2_t{hv[4], hv[5]}, a2);
            a3 = dot2_acc(w[j * 4 + 3], half2_t{hv[6], hv[7]}, a3);
        }
        const float pre = (a0 + a1) + (a2 + a3);

        const float r = fmaxf(pre, 0.0f);
        h = one_m * h + alpha * (r + rn);

        ob[(t + 1) * N_ + n] = h;                 // coalesced fp32 store
        hbuf[(t + 1) & 1][n] = (_Float16)h;       // next step's broadcast buffer
        __syncthreads();                          // one barrier per step (double-buffered h)
    }
}

extern "C" void kernel_launch(void* const* d_in, const int* in_sizes, int n_in,
                              void* d_out, int out_size, void* d_ws, size_t ws_size,
                              hipStream_t stream) {
    const float* u    = (const float*)d_in[0];
    const float* unz  = (const float*)d_in[1];
    const float* rnz  = (const float*)d_in[2];
    const float* Wrec = (const float*)d_in[3];
    const float* brec = (const float*)d_in[4];
    const float* Win  = (const float*)d_in[5];
    float* out = (float*)d_out;

    rnn_scan_kernel<<<dim3(B_), dim3(N_), 0, stream>>>(u, unz, rnz, Wrec, brec, Win, out);
}

// Round 2
// 2334.901 us; speedup vs baseline: 1.1128x; 1.1128x over previous
//
#include <hip/hip_runtime.h>

// RNN scan: h_{t+1} = 0.8*h_t + 0.2*(relu(h_t @ W_rec^T + b_rec + inp_t) + rn_t)
// 128 chains -> 128 blocks x 512 threads. Thread n owns row n of W_rec.
//
// W_rec (512x512 fp16 = 512 KB) cannot be fully register-resident: a CU's
// whole register file is 512 KB. Split:
//   cols [0,K1)   -> 200 half2 VGPRs per thread (K1=400)
//   cols [K1,512) -> fp16 in d_ws [NG][512] (16B/row-group), streamed from L2
// h broadcast: ONE ds_read_b128 per lane (lane l holds h[8l..8l+8]) then
// v_readlane (constant lane idx, unrolled) feeds the SGPR operand of
// v_dot2_f32_f16 -- avoids the 512 KB/step LDS broadcast fan-out.

#define B_  128
#define T_  512
#define N_  512
#define IN_ 6

#define K1   400              // columns held in VGPRs
#define NREG (K1 / 2)         // 200 half2 registers
#define NG   ((N_ - K1) / 8)  // 14 streamed tail groups of 8 cols
#define NGH  (NG / 2)         // 7 (two halves to bound live loads)

typedef _Float16 half2_t __attribute__((ext_vector_type(2)));

#if __has_builtin(__builtin_amdgcn_fdot2)
#define HAVE_FDOT2 1
#else
#define HAVE_FDOT2 0
#endif

__device__ __forceinline__ float dot2_acc(half2_t a, half2_t b, float c) {
#if HAVE_FDOT2
    return __builtin_amdgcn_fdot2(a, b, c, false);
#else
    c = fmaf((float)a[0], (float)b[0], c);
    c = fmaf((float)a[1], (float)b[1], c);
    return c;
#endif
}

__device__ __forceinline__ half2_t h2bits(unsigned s) {
    union { unsigned u; half2_t h; } cv; cv.u = s; return cv.h;
}

// ---- prep: W_rec cols [K1,512) -> fp16, layout [NG][N_] of 16B (8 halfs) ----
__global__ void prep_tail_kernel(const float* __restrict__ Wrec,
                                 uint4* __restrict__ ws) {
    int tid = blockIdx.x * blockDim.x + threadIdx.x;
    if (tid >= NG * N_) return;
    int g = tid / N_, n = tid % N_;
    const float* src = Wrec + (size_t)n * N_ + K1 + g * 8;
    union { unsigned u[4]; half2_t h[4]; } cv;
#pragma unroll
    for (int p = 0; p < 4; ++p)
        cv.h[p] = half2_t{(_Float16)src[2 * p], (_Float16)src[2 * p + 1]};
    ws[(size_t)g * N_ + n] = uint4{cv.u[0], cv.u[1], cv.u[2], cv.u[3]};
}

template <bool USE_WS>
__device__ __forceinline__ uint4 load_tail(const uint4* __restrict__ ws,
                                           const float* __restrict__ Wrec,
                                           int g, int n) {
    if constexpr (USE_WS) {
        return ws[(size_t)g * N_ + n];
    } else {
        const float4* s4 = (const float4*)(Wrec + (size_t)n * N_ + K1 + g * 8);
        float4 f0 = s4[0], f1 = s4[1];
        union { unsigned u[4]; half2_t h[4]; } cv;
        cv.h[0] = half2_t{(_Float16)f0.x, (_Float16)f0.y};
        cv.h[1] = half2_t{(_Float16)f0.z, (_Float16)f0.w};
        cv.h[2] = half2_t{(_Float16)f1.x, (_Float16)f1.y};
        cv.h[3] = half2_t{(_Float16)f1.z, (_Float16)f1.w};
        return uint4{cv.u[0], cv.u[1], cv.u[2], cv.u[3]};
    }
}

template <bool USE_WS>
__global__ __launch_bounds__(512, 2) void rnn_scan_kernel(
    const float* __restrict__ u,     // [B,T,IN]
    const float* __restrict__ unz,   // [B,T,IN]
    const float* __restrict__ rnz,   // [B,T,N]
    const float* __restrict__ Wrec,  // [N,N]
    const float* __restrict__ brec,  // [N]
    const float* __restrict__ Win,   // [N,IN]
    const uint4* __restrict__ ws,    // fp16 tail [NG][N_]
    float* __restrict__ out)         // [B,T,N]
{
    const int b = blockIdx.x;
    const int n = threadIdx.x;
    const int lane = n & 63;

    __shared__ __align__(16) _Float16 hbuf[2][N_];   // 2 KB double buffer

    // one-time: W row n cols [0,K1) -> 200 half2 VGPRs
    half2_t w[NREG];
    {
        const float2* wrow = (const float2*)(Wrec + (size_t)n * N_);
#pragma unroll
        for (int j = 0; j < NREG; ++j) {
            float2 f = wrow[j];
            w[j] = half2_t{(_Float16)f.x, (_Float16)f.y};
        }
    }
    float win[IN_];
#pragma unroll
    for (int i = 0; i < IN_; ++i) win[i] = Win[n * IN_ + i];
    const float br = brec[n];

    const float alpha  = 0.2f;
    const float one_m  = 0.8f;
    const float nscale = 0.6324555320336759f;  // sqrt(2/alpha * sigma^2)

    float h = 0.0f;
    float* ob = out + (size_t)b * T_ * N_;
    ob[n] = 0.0f;
    hbuf[0][n] = (_Float16)0.0f;
    __syncthreads();

    const float* ub = u   + (size_t)b * T_ * IN_;
    const float* nb = unz + (size_t)b * T_ * IN_;
    const float* rb = rnz + (size_t)b * T_ * N_;

    for (int t = 0; t < T_ - 1; ++t) {
        // full h for this wave: one b128 per lane (lane l -> h[8l..8l+8])
        uint4 hv = ((const uint4*)hbuf[t & 1])[lane];
        int hvv[4] = {(int)hv.x, (int)hv.y, (int)hv.z, (int)hv.w};

        // prefetch first tail half + this step's noise/input (hide under dots)
        uint4 wv[NGH];
#pragma unroll
        for (int g = 0; g < NGH; ++g) wv[g] = load_tail<USE_WS>(ws, Wrec, g, n);
        const float rn = rb[t * N_ + n];
        float ubt[IN_], nbt[IN_];
#pragma unroll
        for (int i = 0; i < IN_; ++i) { ubt[i] = ub[t * IN_ + i]; nbt[i] = nb[t * IN_ + i]; }

        float a[4];
        a[0] = br; a[1] = 0.0f; a[2] = 0.0f; a[3] = 0.0f;
#pragma unroll
        for (int i = 0; i < IN_; ++i)
            a[0] = fmaf(win[i], fmaf(nscale, nbt[i], ubt[i]), a[0]);

        // register part: cols [0,K1): readlane broadcasts h pair -> SGPR operand
#pragma unroll
        for (int j = 0; j < NREG; ++j) {
            unsigned s = (unsigned)__builtin_amdgcn_readlane(hvv[j & 3], j >> 2);
            a[j & 3] = dot2_acc(w[j], h2bits(s), a[j & 3]);
        }

        // streamed tail, first half (groups 0..NGH)
#pragma unroll
        for (int g = 0; g < NGH; ++g) {
#pragma unroll
            for (int p = 0; p < 4; ++p) {
                unsigned s = (unsigned)__builtin_amdgcn_readlane(hvv[p], K1 / 8 + g);
                a[p] = dot2_acc(h2bits(((const unsigned*)&wv[g])[p]), h2bits(s), a[p]);
            }
        }
        // second half
#pragma unroll
        for (int g = 0; g < NGH; ++g) wv[g] = load_tail<USE_WS>(ws, Wrec, NGH + g, n);
#pragma unroll
        for (int g = 0; g < NGH; ++g) {
#pragma unroll
            for (int p = 0; p < 4; ++p) {
                unsigned s = (unsigned)__builtin_amdgcn_readlane(hvv[p], K1 / 8 + NGH + g);
                a[p] = dot2_acc(h2bits(((const unsigned*)&wv[g])[p]), h2bits(s), a[p]);
            }
        }

        const float pre = (a[0] + a[1]) + (a[2] + a[3]);
        const float r = fmaxf(pre, 0.0f);
        h = one_m * h + alpha * (r + rn);

        ob[(t + 1) * N_ + n] = h;            // coalesced fp32 store
        hbuf[(t + 1) & 1][n] = (_Float16)h;  // next step's broadcast source
        __syncthreads();
    }
}

extern "C" void kernel_launch(void* const* d_in, const int* in_sizes, int n_in,
                              void* d_out, int out_size, void* d_ws, size_t ws_size,
                              hipStream_t stream) {
    const float* u    = (const float*)d_in[0];
    const float* unz  = (const float*)d_in[1];
    const float* rnz  = (const float*)d_in[2];
    const float* Wrec = (const float*)d_in[3];
    const float* brec = (const float*)d_in[4];
    const float* Win  = (const float*)d_in[5];
    float* out = (float*)d_out;

    const size_t ws_need = (size_t)NG * N_ * sizeof(uint4);  // 114688 B
    if (ws_size >= ws_need) {
        uint4* ws = (uint4*)d_ws;
        prep_tail_kernel<<<(NG * N_ + 255) / 256, 256, 0, stream>>>(Wrec, ws);
        rnn_scan_kernel<true><<<dim3(B_), dim3(N_), 0, stream>>>(
            u, unz, rnz, Wrec, brec, Win, ws, out);
    } else {
        rnn_scan_kernel<false><<<dim3(B_), dim3(N_), 0, stream>>>(
            u, unz, rnz, Wrec, brec, Win, nullptr, out);
    }
}

// Round 3
// 2162.478 us; speedup vs baseline: 1.2016x; 1.0797x over previous
//
#include <hip/hip_runtime.h>

// RNN scan: h_{t+1} = 0.8*h_t + 0.2*(relu(h_t @ W_rec^T + b_rec + inp_t) + rn_t)
// 128 chains -> 128 blocks x 512 threads, thread n owns row n of W_rec (fp16).
//
// W row (512 cols = 64 groups of 8 cols) split three ways:
//   groups  0..39 -> 40 NAMED uint4 SSA values (160 VGPRs) -- named vars, not an
//                    array: LLVM demotes big local arrays to scratch (R0/R1 bug:
//                    VGPR_Count=128 with w[200] -> per-step scratch reload).
//   groups 40..46 -> LDS ltail[g][n] (57 KB, conflict-free b128 reads)
//   groups 47..63 -> fp16 image in d_ws [17][512] uint4, streamed from L2 each
//                    step in 3 batches interleaved with dot phases.
// h broadcast: one ds_read_b128 per lane (lane l holds h[8l..8l+8]), then
// v_readlane (constant lane index) feeds the SGPR operand of v_dot2_f32_f16.

#define B_  128
#define T_  512
#define N_  512
#define IN_ 6

#define NREGG  40                    // groups in VGPRs   (cols 0..320)
#define NLDSG  7                     // groups in LDS     (cols 320..376)
#define NWSG   17                    // groups from d_ws  (cols 376..512)
#define LDS_C0 (8 * NREGG)           // 320
#define WS_C0  (8 * (NREGG + NLDSG)) // 376

typedef _Float16 half2_t __attribute__((ext_vector_type(2)));

#if __has_builtin(__builtin_amdgcn_fdot2)
#define HAVE_FDOT2 1
#else
#define HAVE_FDOT2 0
#endif

__device__ __forceinline__ float dot2_acc(half2_t a, half2_t b, float c) {
#if HAVE_FDOT2
    return __builtin_amdgcn_fdot2(a, b, c, false);
#else
    c = fmaf((float)a[0], (float)b[0], c);
    c = fmaf((float)a[1], (float)b[1], c);
    return c;
#endif
}

__device__ __forceinline__ half2_t h2bits(unsigned s) {
    union { unsigned u; half2_t h; } cv; cv.u = s; return cv.h;
}

// 8 consecutive fp32 -> 8 packed fp16 in a uint4
__device__ __forceinline__ uint4 pack8(const float* __restrict__ p) {
    const float4 f0 = ((const float4*)p)[0];
    const float4 f1 = ((const float4*)p)[1];
    union { unsigned u[4]; half2_t h[4]; } cv;
    cv.h[0] = half2_t{(_Float16)f0.x, (_Float16)f0.y};
    cv.h[1] = half2_t{(_Float16)f0.z, (_Float16)f0.w};
    cv.h[2] = half2_t{(_Float16)f1.x, (_Float16)f1.y};
    cv.h[3] = half2_t{(_Float16)f1.z, (_Float16)f1.w};
    return uint4{cv.u[0], cv.u[1], cv.u[2], cv.u[3]};
}

// ---- prep: W_rec cols [376,512) -> fp16 image, layout [NWSG][N_] uint4 ----
__global__ void prep_tail_kernel(const float* __restrict__ Wrec,
                                 uint4* __restrict__ ws) {
    int tid = blockIdx.x * blockDim.x + threadIdx.x;
    if (tid >= NWSG * N_) return;
    int g = tid >> 9, n = tid & (N_ - 1);
    ws[(size_t)g * N_ + n] = pack8(Wrec + (size_t)n * N_ + WS_C0 + 8 * g);
}

template <bool USE_WS>
__device__ __forceinline__ uint4 gload(const uint4* __restrict__ wsn,
                                       const float* __restrict__ wrow_ws, int g) {
    if constexpr (USE_WS) return wsn[g * N_];
    else return pack8(wrow_ws + 8 * g);
}

// one 8-col group: 4 readlane-broadcast h pairs dotted into 4 accumulators
#define DOTG(W, G) do {                                                               \
    a0 = dot2_acc(h2bits((W).x), h2bits((unsigned)__builtin_amdgcn_readlane(hx,(G))), a0); \
    a1 = dot2_acc(h2bits((W).y), h2bits((unsigned)__builtin_amdgcn_readlane(hy,(G))), a1); \
    a2 = dot2_acc(h2bits((W).z), h2bits((unsigned)__builtin_amdgcn_readlane(hz,(G))), a2); \
    a3 = dot2_acc(h2bits((W).w), h2bits((unsigned)__builtin_amdgcn_readlane(hw,(G))), a3); \
} while (0)

template <bool USE_WS>
__global__ __launch_bounds__(512, 2) void rnn_scan_kernel(
    const float* __restrict__ u,     // [B,T,IN]
    const float* __restrict__ unz,   // [B,T,IN]
    const float* __restrict__ rnz,   // [B,T,N]
    const float* __restrict__ Wrec,  // [N,N]
    const float* __restrict__ brec,  // [N]
    const float* __restrict__ Win,   // [N,IN]
    const uint4* __restrict__ ws,    // fp16 tail image [NWSG][N_]
    float* __restrict__ out)         // [B,T,N]
{
    const int b = blockIdx.x;
    const int n = threadIdx.x;
    const int lane = n & 63;

    __shared__ uint4 ltail[NLDSG][N_];               // 57344 B
    __shared__ __align__(16) _Float16 hbuf[2][N_];   // 2048 B

    const float* wrow = Wrec + (size_t)n * N_;

    // ---- one-time: groups 0..39 as 40 NAMED uint4 (160 VGPRs, SSA values) ----
    uint4 w0  = pack8(wrow +   0), w1  = pack8(wrow +   8), w2  = pack8(wrow +  16), w3  = pack8(wrow +  24);
    uint4 w4  = pack8(wrow +  32), w5  = pack8(wrow +  40), w6  = pack8(wrow +  48), w7  = pack8(wrow +  56);
    uint4 w8  = pack8(wrow +  64), w9  = pack8(wrow +  72), w10 = pack8(wrow +  80), w11 = pack8(wrow +  88);
    uint4 w12 = pack8(wrow +  96), w13 = pack8(wrow + 104), w14 = pack8(wrow + 112), w15 = pack8(wrow + 120);
    uint4 w16 = pack8(wrow + 128), w17 = pack8(wrow + 136), w18 = pack8(wrow + 144), w19 = pack8(wrow + 152);
    uint4 w20 = pack8(wrow + 160), w21 = pack8(wrow + 168), w22 = pack8(wrow + 176), w23 = pack8(wrow + 184);
    uint4 w24 = pack8(wrow + 192), w25 = pack8(wrow + 200), w26 = pack8(wrow + 208), w27 = pack8(wrow + 216);
    uint4 w28 = pack8(wrow + 224), w29 = pack8(wrow + 232), w30 = pack8(wrow + 240), w31 = pack8(wrow + 248);
    uint4 w32 = pack8(wrow + 256), w33 = pack8(wrow + 264), w34 = pack8(wrow + 272), w35 = pack8(wrow + 280);
    uint4 w36 = pack8(wrow + 288), w37 = pack8(wrow + 296), w38 = pack8(wrow + 304), w39 = pack8(wrow + 312);

    // ---- one-time: groups 40..46 into LDS ----
#pragma unroll
    for (int j = 0; j < NLDSG; ++j)
        ltail[j][n] = pack8(wrow + LDS_C0 + 8 * j);

    const float win0 = Win[n * IN_ + 0], win1 = Win[n * IN_ + 1], win2 = Win[n * IN_ + 2];
    const float win3 = Win[n * IN_ + 3], win4 = Win[n * IN_ + 4], win5 = Win[n * IN_ + 5];
    const float br = brec[n];
    const uint4* wsn = ws + n;
    const float* wrow_ws = wrow + WS_C0;

    const float NS = 0.6324555320336759f;  // sqrt(2/alpha * sigma^2)
    float h = 0.0f;

    float* ob = out + (size_t)b * T_ * N_;
    const float* rb = rnz + (size_t)b * T_ * N_;
    const float2* ubp = (const float2*)(u   + (size_t)b * T_ * IN_);
    const float2* nbp = (const float2*)(unz + (size_t)b * T_ * IN_);

    hbuf[0][n] = (_Float16)0.0f;

    // inp for t=0
    float2 cu0 = ubp[0], cu1 = ubp[1], cu2 = ubp[2];
    float2 cn0 = nbp[0], cn1 = nbp[1], cn2 = nbp[2];
    float inp_c = br;
    inp_c = fmaf(win0, fmaf(NS, cn0.x, cu0.x), inp_c);
    inp_c = fmaf(win1, fmaf(NS, cn0.y, cu0.y), inp_c);
    inp_c = fmaf(win2, fmaf(NS, cn1.x, cu1.x), inp_c);
    inp_c = fmaf(win3, fmaf(NS, cn1.y, cu1.y), inp_c);
    inp_c = fmaf(win4, fmaf(NS, cn2.x, cu2.x), inp_c);
    inp_c = fmaf(win5, fmaf(NS, cn2.y, cu2.y), inp_c);
    float rn_c = rb[n];
    __syncthreads();

    for (int t = 0; t < T_ - 1; ++t) {
        ob[(size_t)t * N_ + n] = h;   // states[t] (t=0: zeros); store early, drains by barrier

        // stream batch A (ws groups 0..5 -> col groups 47..52)
        uint4 ga0 = gload<USE_WS>(wsn, wrow_ws, 0), ga1 = gload<USE_WS>(wsn, wrow_ws, 1);
        uint4 ga2 = gload<USE_WS>(wsn, wrow_ws, 2), ga3 = gload<USE_WS>(wsn, wrow_ws, 3);
        uint4 ga4 = gload<USE_WS>(wsn, wrow_ws, 4), ga5 = gload<USE_WS>(wsn, wrow_ws, 5);

        // prefetch t+1 inputs
        const float rn_n = rb[(t + 1) * N_ + n];
        const float2 pu0 = ubp[(t + 1) * 3 + 0], pu1 = ubp[(t + 1) * 3 + 1], pu2 = ubp[(t + 1) * 3 + 2];
        const float2 pn0 = nbp[(t + 1) * 3 + 0], pn1 = nbp[(t + 1) * 3 + 1], pn2 = nbp[(t + 1) * 3 + 2];

        // this wave's copy of full h: lane l -> h[8l..8l+8]
        const uint4 hv = ((const uint4*)hbuf[t & 1])[lane];
        const int hx = (int)hv.x, hy = (int)hv.y, hz = (int)hv.z, hw = (int)hv.w;

        float a0 = inp_c, a1 = 0.0f, a2 = 0.0f, a3 = 0.0f;

        DOTG(w0, 0);  DOTG(w1, 1);  DOTG(w2, 2);  DOTG(w3, 3);
        DOTG(w4, 4);  DOTG(w5, 5);  DOTG(w6, 6);  DOTG(w7, 7);
        DOTG(w8, 8);  DOTG(w9, 9);  DOTG(w10, 10); DOTG(w11, 11);
        DOTG(w12, 12); DOTG(w13, 13); DOTG(w14, 14); DOTG(w15, 15);

        DOTG(ga0, 47); DOTG(ga1, 48); DOTG(ga2, 49);
        DOTG(ga3, 50); DOTG(ga4, 51); DOTG(ga5, 52);

        // stream batch B (ws groups 6..11 -> col groups 53..58)
        uint4 gb0 = gload<USE_WS>(wsn, wrow_ws, 6),  gb1 = gload<USE_WS>(wsn, wrow_ws, 7);
        uint4 gb2 = gload<USE_WS>(wsn, wrow_ws, 8),  gb3 = gload<USE_WS>(wsn, wrow_ws, 9);
        uint4 gb4 = gload<USE_WS>(wsn, wrow_ws, 10), gb5 = gload<USE_WS>(wsn, wrow_ws, 11);

        DOTG(w16, 16); DOTG(w17, 17); DOTG(w18, 18); DOTG(w19, 19);
        DOTG(w20, 20); DOTG(w21, 21); DOTG(w22, 22); DOTG(w23, 23);
        DOTG(w24, 24); DOTG(w25, 25); DOTG(w26, 26); DOTG(w27, 27);
        DOTG(w28, 28); DOTG(w29, 29); DOTG(w30, 30); DOTG(w31, 31);

        DOTG(gb0, 53); DOTG(gb1, 54); DOTG(gb2, 55);
        DOTG(gb3, 56); DOTG(gb4, 57); DOTG(gb5, 58);

        // stream batch C (ws groups 12..16 -> col groups 59..63) + LDS reads
        uint4 gc0 = gload<USE_WS>(wsn, wrow_ws, 12), gc1 = gload<USE_WS>(wsn, wrow_ws, 13);
        uint4 gc2 = gload<USE_WS>(wsn, wrow_ws, 14), gc3 = gload<USE_WS>(wsn, wrow_ws, 15);
        uint4 gc4 = gload<USE_WS>(wsn, wrow_ws, 16);
        uint4 la0 = ltail[0][n], la1 = ltail[1][n], la2 = ltail[2][n], la3 = ltail[3][n];

        DOTG(w32, 32); DOTG(w33, 33); DOTG(w34, 34); DOTG(w35, 35);
        DOTG(w36, 36); DOTG(w37, 37); DOTG(w38, 38); DOTG(w39, 39);

        uint4 lb0 = ltail[4][n], lb1 = ltail[5][n], lb2 = ltail[6][n];

        DOTG(la0, 40); DOTG(la1, 41); DOTG(la2, 42); DOTG(la3, 43);
        DOTG(lb0, 44); DOTG(lb1, 45); DOTG(lb2, 46);
        DOTG(gc0, 59); DOTG(gc1, 60); DOTG(gc2, 61); DOTG(gc3, 62); DOTG(gc4, 63);

        const float pre = (a0 + a1) + (a2 + a3);
        h = 0.8f * h + 0.2f * (fmaxf(pre, 0.0f) + rn_c);
        hbuf[(t + 1) & 1][n] = (_Float16)h;

        float inp_n = br;
        inp_n = fmaf(win0, fmaf(NS, pn0.x, pu0.x), inp_n);
        inp_n = fmaf(win1, fmaf(NS, pn0.y, pu0.y), inp_n);
        inp_n = fmaf(win2, fmaf(NS, pn1.x, pu1.x), inp_n);
        inp_n = fmaf(win3, fmaf(NS, pn1.y, pu1.y), inp_n);
        inp_n = fmaf(win4, fmaf(NS, pn2.x, pu2.x), inp_n);
        inp_n = fmaf(win5, fmaf(NS, pn2.y, pu2.y), inp_n);
        inp_c = inp_n;
        rn_c  = rn_n;
        __syncthreads();
    }
    ob[(size_t)(T_ - 1) * N_ + n] = h;  // states[511]
}

extern "C" void kernel_launch(void* const* d_in, const int* in_sizes, int n_in,
                              void* d_out, int out_size, void* d_ws, size_t ws_size,
                              hipStream_t stream) {
    const float* u    = (const float*)d_in[0];
    const float* unz  = (const float*)d_in[1];
    const float* rnz  = (const float*)d_in[2];
    const float* Wrec = (const float*)d_in[3];
    const float* brec = (const float*)d_in[4];
    const float* Win  = (const float*)d_in[5];
    float* out = (float*)d_out;

    const size_t ws_need = (size_t)NWSG * N_ * sizeof(uint4);  // 139264 B
    if (ws_size >= ws_need) {
        uint4* ws = (uint4*)d_ws;
        prep_tail_kernel<<<(NWSG * N_ + 255) / 256, 256, 0, stream>>>(Wrec, ws);
        rnn_scan_kernel<true><<<dim3(B_), dim3(N_), 0, stream>>>(
            u, unz, rnz, Wrec, brec, Win, ws, out);
    } else {
        rnn_scan_kernel<false><<<dim3(B_), dim3(N_), 0, stream>>>(
            u, unz, rnz, Wrec, brec, Win, nullptr, out);
    }
}

// Round 4
// 2011.868 us; speedup vs baseline: 1.2915x; 1.0749x over previous
//
#include <hip/hip_runtime.h>

// RNN scan: h_{t+1} = 0.8*h_t + 0.2*(relu(h_t @ W_rec^T + b_rec + inp_t) + rn_t)
// 128 chains -> 128 blocks x 512 threads, thread n owns row n of W_rec (fp16).
//
// W row = 64 groups of 8 cols, split:
//   groups  0..43 -> 44 NAMED uint4 SSA values (176 VGPRs)
//   groups 44..50 -> LDS ltail[7][512] uint4 (57 KB, static-LDS cap is 64 KB)
//   groups 51..63 -> fp16 image in d_ws, streamed from L2 each step (104 KB/CU)
//
// WHY amdgpu_waves_per_eu(2,2): the backend budgets VGPRs from ACHIEVABLE
// occupancy (R1-R3: LDS allowed 2 blocks/CU -> 4 waves/EU -> budget 128 ->
// the allocator rematerialized the W loads into the loop = W re-fetched from
// L1/L2 + re-converted every step; VGPR_Count=128, VALUBusy 37%, ~2 ms).
// Pinning max occupancy to 2 waves/EU gives a 256-reg budget (8 waves x 256
// = the full 512 KB CU register file, 1 block/CU).
// WHY the asm "+v" barriers: makes each W component an opaque asm result so
// rematerialization of the global load is impossible.
//
// h broadcast: one ds_read_b128 per lane (lane l holds h[8l..8l+8]), then
// v_readlane with constant lane index feeds v_dot2_f32_f16's SGPR operand:
// zero LDS fan-out traffic (R0's per-thread LDS broadcast was LDS-BW bound).

#define B_  128
#define T_  512
#define N_  512
#define IN_ 6

#define NREGG  44                    // groups in VGPRs   (cols 0..352)
#define NLDSG  7                     // groups in LDS     (cols 352..408)
#define NWSG   13                    // groups from d_ws  (cols 408..512)
#define LDS_C0 (8 * NREGG)           // 352
#define WS_C0  (8 * (NREGG + NLDSG)) // 408

typedef _Float16 half2_t __attribute__((ext_vector_type(2)));

#if __has_builtin(__builtin_amdgcn_fdot2)
#define HAVE_FDOT2 1
#else
#define HAVE_FDOT2 0
#endif

__device__ __forceinline__ float dot2_acc(half2_t a, half2_t b, float c) {
#if HAVE_FDOT2
    return __builtin_amdgcn_fdot2(a, b, c, false);
#else
    c = fmaf((float)a[0], (float)b[0], c);
    c = fmaf((float)a[1], (float)b[1], c);
    return c;
#endif
}

__device__ __forceinline__ half2_t h2bits(unsigned s) {
    union { unsigned u; half2_t h; } cv; cv.u = s; return cv.h;
}

// 8 consecutive fp32 -> 8 packed fp16 in a uint4
__device__ __forceinline__ uint4 pack8(const float* __restrict__ p) {
    const float4 f0 = ((const float4*)p)[0];
    const float4 f1 = ((const float4*)p)[1];
    union { unsigned u[4]; half2_t h[4]; } cv;
    cv.h[0] = half2_t{(_Float16)f0.x, (_Float16)f0.y};
    cv.h[1] = half2_t{(_Float16)f0.z, (_Float16)f0.w};
    cv.h[2] = half2_t{(_Float16)f1.x, (_Float16)f1.y};
    cv.h[3] = half2_t{(_Float16)f1.z, (_Float16)f1.w};
    return uint4{cv.u[0], cv.u[1], cv.u[2], cv.u[3]};
}

// opaque redefinition: blocks rematerialization of the producing load
#define KEEP4(v) asm volatile("" : "+v"((v).x), "+v"((v).y), "+v"((v).z), "+v"((v).w))

// ---- prep: W_rec cols [WS_C0,512) -> fp16 image, layout [NWSG][N_] uint4 ----
__global__ void prep_tail_kernel(const float* __restrict__ Wrec,
                                 uint4* __restrict__ ws) {
    int tid = blockIdx.x * blockDim.x + threadIdx.x;
    if (tid >= NWSG * N_) return;
    int g = tid >> 9, n = tid & (N_ - 1);
    ws[(size_t)g * N_ + n] = pack8(Wrec + (size_t)n * N_ + WS_C0 + 8 * g);
}

template <bool USE_WS>
__device__ __forceinline__ uint4 gload(const uint4* __restrict__ wsn,
                                       const float* __restrict__ wrow_ws, int g) {
    if constexpr (USE_WS) return wsn[g * N_];
    else return pack8(wrow_ws + 8 * g);
}

// one 8-col group: 4 readlane-broadcast h pairs dotted into 4 accumulators
#define DOTG(W, G) do {                                                                    \
    a0 = dot2_acc(h2bits((W).x), h2bits((unsigned)__builtin_amdgcn_readlane(hx,(G))), a0); \
    a1 = dot2_acc(h2bits((W).y), h2bits((unsigned)__builtin_amdgcn_readlane(hy,(G))), a1); \
    a2 = dot2_acc(h2bits((W).z), h2bits((unsigned)__builtin_amdgcn_readlane(hz,(G))), a2); \
    a3 = dot2_acc(h2bits((W).w), h2bits((unsigned)__builtin_amdgcn_readlane(hw,(G))), a3); \
} while (0)

template <bool USE_WS>
__global__ __launch_bounds__(512)
__attribute__((amdgpu_waves_per_eu(2, 2)))
void rnn_scan_kernel(
    const float* __restrict__ u,     // [B,T,IN]
    const float* __restrict__ unz,   // [B,T,IN]
    const float* __restrict__ rnz,   // [B,T,N]
    const float* __restrict__ Wrec,  // [N,N]
    const float* __restrict__ brec,  // [N]
    const float* __restrict__ Win,   // [N,IN]
    const uint4* __restrict__ ws,    // fp16 tail image [NWSG][N_]
    float* __restrict__ out)         // [B,T,N]
{
    const int b = blockIdx.x;
    const int n = threadIdx.x;
    const int lane = n & 63;

    __shared__ uint4 ltail[NLDSG][N_];               // 57344 B
    __shared__ __align__(16) _Float16 hbuf[2][N_];   // 2048 B

    const float* wrow = Wrec + (size_t)n * N_;

    // ---- one-time: groups 0..43 as 44 NAMED uint4 (176 VGPRs) ----
    uint4 w0  = pack8(wrow +   0); uint4 w1  = pack8(wrow +   8); uint4 w2  = pack8(wrow +  16); uint4 w3  = pack8(wrow +  24);
    uint4 w4  = pack8(wrow +  32); uint4 w5  = pack8(wrow +  40); uint4 w6  = pack8(wrow +  48); uint4 w7  = pack8(wrow +  56);
    uint4 w8  = pack8(wrow +  64); uint4 w9  = pack8(wrow +  72); uint4 w10 = pack8(wrow +  80); uint4 w11 = pack8(wrow +  88);
    uint4 w12 = pack8(wrow +  96); uint4 w13 = pack8(wrow + 104); uint4 w14 = pack8(wrow + 112); uint4 w15 = pack8(wrow + 120);
    uint4 w16 = pack8(wrow + 128); uint4 w17 = pack8(wrow + 136); uint4 w18 = pack8(wrow + 144); uint4 w19 = pack8(wrow + 152);
    uint4 w20 = pack8(wrow + 160); uint4 w21 = pack8(wrow + 168); uint4 w22 = pack8(wrow + 176); uint4 w23 = pack8(wrow + 184);
    uint4 w24 = pack8(wrow + 192); uint4 w25 = pack8(wrow + 200); uint4 w26 = pack8(wrow + 208); uint4 w27 = pack8(wrow + 216);
    uint4 w28 = pack8(wrow + 224); uint4 w29 = pack8(wrow + 232); uint4 w30 = pack8(wrow + 240); uint4 w31 = pack8(wrow + 248);
    uint4 w32 = pack8(wrow + 256); uint4 w33 = pack8(wrow + 264); uint4 w34 = pack8(wrow + 272); uint4 w35 = pack8(wrow + 280);
    uint4 w36 = pack8(wrow + 288); uint4 w37 = pack8(wrow + 296); uint4 w38 = pack8(wrow + 304); uint4 w39 = pack8(wrow + 312);
    uint4 w40 = pack8(wrow + 320); uint4 w41 = pack8(wrow + 328); uint4 w42 = pack8(wrow + 336); uint4 w43 = pack8(wrow + 344);

    KEEP4(w0);  KEEP4(w1);  KEEP4(w2);  KEEP4(w3);  KEEP4(w4);  KEEP4(w5);  KEEP4(w6);  KEEP4(w7);
    KEEP4(w8);  KEEP4(w9);  KEEP4(w10); KEEP4(w11); KEEP4(w12); KEEP4(w13); KEEP4(w14); KEEP4(w15);
    KEEP4(w16); KEEP4(w17); KEEP4(w18); KEEP4(w19); KEEP4(w20); KEEP4(w21); KEEP4(w22); KEEP4(w23);
    KEEP4(w24); KEEP4(w25); KEEP4(w26); KEEP4(w27); KEEP4(w28); KEEP4(w29); KEEP4(w30); KEEP4(w31);
    KEEP4(w32); KEEP4(w33); KEEP4(w34); KEEP4(w35); KEEP4(w36); KEEP4(w37); KEEP4(w38); KEEP4(w39);
    KEEP4(w40); KEEP4(w41); KEEP4(w42); KEEP4(w43);

    // ---- one-time: groups 44..50 into LDS ----
#pragma unroll
    for (int j = 0; j < NLDSG; ++j)
        ltail[j][n] = pack8(wrow + LDS_C0 + 8 * j);

    const float win0 = Win[n * IN_ + 0], win1 = Win[n * IN_ + 1], win2 = Win[n * IN_ + 2];
    const float win3 = Win[n * IN_ + 3], win4 = Win[n * IN_ + 4], win5 = Win[n * IN_ + 5];
    const float br = brec[n];
    const uint4* wsn = ws + n;
    const float* wrow_ws = wrow + WS_C0;

    const float NS = 0.6324555320336759f;  // sqrt(2/alpha * sigma^2)
    float h = 0.0f;

    float* ob = out + (size_t)b * T_ * N_;
    const float* rb = rnz + (size_t)b * T_ * N_;
    const float2* ubp = (const float2*)(u   + (size_t)b * T_ * IN_);
    const float2* nbp = (const float2*)(unz + (size_t)b * T_ * IN_);

    hbuf[0][n] = (_Float16)0.0f;

    // inp for t=0
    float2 cu0 = ubp[0], cu1 = ubp[1], cu2 = ubp[2];
    float2 cn0 = nbp[0], cn1 = nbp[1], cn2 = nbp[2];
    float inp_c = br;
    inp_c = fmaf(win0, fmaf(NS, cn0.x, cu0.x), inp_c);
    inp_c = fmaf(win1, fmaf(NS, cn0.y, cu0.y), inp_c);
    inp_c = fmaf(win2, fmaf(NS, cn1.x, cu1.x), inp_c);
    inp_c = fmaf(win3, fmaf(NS, cn1.y, cu1.y), inp_c);
    inp_c = fmaf(win4, fmaf(NS, cn2.x, cu2.x), inp_c);
    inp_c = fmaf(win5, fmaf(NS, cn2.y, cu2.y), inp_c);
    float rn_c = rb[n];
    __syncthreads();

#pragma unroll 1
    for (int t = 0; t < T_ - 1; ++t) {
        ob[(size_t)t * N_ + n] = h;   // states[t] (t=0: zeros)

        // this wave's copy of full h: lane l -> h[8l..8l+8]
        const uint4 hv = ((const uint4*)hbuf[t & 1])[lane];
        const int hx = (int)hv.x, hy = (int)hv.y, hz = (int)hv.z, hw = (int)hv.w;

        // stream batch A (ws groups 0..4 -> col groups 51..55)
        uint4 sa0 = gload<USE_WS>(wsn, wrow_ws, 0), sa1 = gload<USE_WS>(wsn, wrow_ws, 1);
        uint4 sa2 = gload<USE_WS>(wsn, wrow_ws, 2), sa3 = gload<USE_WS>(wsn, wrow_ws, 3);
        uint4 sa4 = gload<USE_WS>(wsn, wrow_ws, 4);

        // prefetch t+1 inputs (consumed after the dots)
        const float rn_n = rb[(t + 1) * N_ + n];
        const float2 pu0 = ubp[(t + 1) * 3 + 0], pu1 = ubp[(t + 1) * 3 + 1], pu2 = ubp[(t + 1) * 3 + 2];
        const float2 pn0 = nbp[(t + 1) * 3 + 0], pn1 = nbp[(t + 1) * 3 + 1], pn2 = nbp[(t + 1) * 3 + 2];

        float a0 = inp_c, a1 = 0.0f, a2 = 0.0f, a3 = 0.0f;

        DOTG(w0, 0);   DOTG(w1, 1);   DOTG(w2, 2);   DOTG(w3, 3);
        DOTG(w4, 4);   DOTG(w5, 5);   DOTG(w6, 6);   DOTG(w7, 7);
        DOTG(w8, 8);   DOTG(w9, 9);   DOTG(w10, 10); DOTG(w11, 11);
        DOTG(w12, 12); DOTG(w13, 13); DOTG(w14, 14); DOTG(w15, 15);

        // stream batch B (ws groups 5..8 -> col groups 56..59)
        uint4 sb0 = gload<USE_WS>(wsn, wrow_ws, 5), sb1 = gload<USE_WS>(wsn, wrow_ws, 6);
        uint4 sb2 = gload<USE_WS>(wsn, wrow_ws, 7), sb3 = gload<USE_WS>(wsn, wrow_ws, 8);

        DOTG(w16, 16); DOTG(w17, 17); DOTG(w18, 18); DOTG(w19, 19);
        DOTG(w20, 20); DOTG(w21, 21); DOTG(w22, 22); DOTG(w23, 23);
        DOTG(sa0, 51); DOTG(sa1, 52); DOTG(sa2, 53); DOTG(sa3, 54); DOTG(sa4, 55);

        // stream batch C (ws groups 9..12 -> col groups 60..63)
        uint4 sc0 = gload<USE_WS>(wsn, wrow_ws, 9),  sc1 = gload<USE_WS>(wsn, wrow_ws, 10);
        uint4 sc2 = gload<USE_WS>(wsn, wrow_ws, 11), sc3 = gload<USE_WS>(wsn, wrow_ws, 12);

        DOTG(w24, 24); DOTG(w25, 25); DOTG(w26, 26); DOTG(w27, 27);
        DOTG(w28, 28); DOTG(w29, 29); DOTG(w30, 30); DOTG(w31, 31);
        DOTG(sb0, 56); DOTG(sb1, 57); DOTG(sb2, 58); DOTG(sb3, 59);

        // LDS batch 1
        uint4 la0 = ltail[0][n], la1 = ltail[1][n], la2 = ltail[2][n], la3 = ltail[3][n];

        DOTG(w32, 32); DOTG(w33, 33); DOTG(w34, 34); DOTG(w35, 35);
        DOTG(w36, 36); DOTG(w37, 37); DOTG(w38, 38); DOTG(w39, 39);

        // LDS batch 2
        uint4 lb0 = ltail[4][n], lb1 = ltail[5][n], lb2 = ltail[6][n];

        DOTG(w40, 40); DOTG(w41, 41); DOTG(w42, 42); DOTG(w43, 43);
        DOTG(la0, 44); DOTG(la1, 45); DOTG(la2, 46); DOTG(la3, 47);
        DOTG(lb0, 48); DOTG(lb1, 49); DOTG(lb2, 50);
        DOTG(sc0, 60); DOTG(sc1, 61); DOTG(sc2, 62); DOTG(sc3, 63);

        const float pre = (a0 + a1) + (a2 + a3);
        h = 0.8f * h + 0.2f * (fmaxf(pre, 0.0f) + rn_c);
        hbuf[(t + 1) & 1][n] = (_Float16)h;

        float inp_n = br;
        inp_n = fmaf(win0, fmaf(NS, pn0.x, pu0.x), inp_n);
        inp_n = fmaf(win1, fmaf(NS, pn0.y, pu0.y), inp_n);
        inp_n = fmaf(win2, fmaf(NS, pn1.x, pu1.x), inp_n);
        inp_n = fmaf(win3, fmaf(NS, pn1.y, pu1.y), inp_n);
        inp_n = fmaf(win4, fmaf(NS, pn2.x, pu2.x), inp_n);
        inp_n = fmaf(win5, fmaf(NS, pn2.y, pu2.y), inp_n);
        inp_c = inp_n;
        rn_c  = rn_n;
        __syncthreads();
    }
    ob[(size_t)(T_ - 1) * N_ + n] = h;  // states[511]
}

extern "C" void kernel_launch(void* const* d_in, const int* in_sizes, int n_in,
                              void* d_out, int out_size, void* d_ws, size_t ws_size,
                              hipStream_t stream) {
    const float* u    = (const float*)d_in[0];
    const float* unz  = (const float*)d_in[1];
    const float* rnz  = (const float*)d_in[2];
    const float* Wrec = (const float*)d_in[3];
    const float* brec = (const float*)d_in[4];
    const float* Win  = (const float*)d_in[5];
    float* out = (float*)d_out;

    const size_t ws_need = (size_t)NWSG * N_ * sizeof(uint4);  // 106496 B
    if (ws_size >= ws_need) {
        uint4* ws = (uint4*)d_ws;
        prep_tail_kernel<<<(NWSG * N_ + 255) / 256, 256, 0, stream>>>(Wrec, ws);
        rnn_scan_kernel<true><<<dim3(B_), dim3(N_), 0, stream>>>(
            u, unz, rnz, Wrec, brec, Win, ws, out);
    } else {
        rnn_scan_kernel<false><<<dim3(B_), dim3(N_), 0, stream>>>(
            u, unz, rnz, Wrec, brec, Win, nullptr, out);
    }
}